// Round 5
// baseline (9621.651 us; speedup 1.0000x reference)
//
#include <hip/hip_runtime.h>
#include <stdint.h>

// S=64, B=64, C=H=E=512, V=32000, steps T=48
// Phase 1: per-b persistent kernel, 64 WGs, ZERO cross-WG sync.
//   Weights for the recurrent matvecs quantized to i8 (per-row scales),
//   B-side (h / h1 / catt) dynamically quantized i8; MFMA i32_16x16x64_i8.
//   Per-XCD L2 working set ~3 MB -> weights stay L2-resident all 48 steps.
// Phase 2: logit tanh GEMM; 3072x32000x512 bf16 GEMM w/ fused exp-rowsum; loss

using bf16x8 = __attribute__((ext_vector_type(8))) short;
using f32x4  = __attribute__((ext_vector_type(4))) float;
using s16x4  = __attribute__((ext_vector_type(4))) short;
using i32x4  = __attribute__((ext_vector_type(4))) int;
typedef unsigned long long u64;
typedef unsigned int u32;

#define DI __device__ __forceinline__

DI short f2bf(float x){
  union { float f; uint32_t u; } v; v.f = x;
  uint32_t r = (v.u + 0x7FFFu + ((v.u >> 16) & 1u)) >> 16;
  return (short)r;
}
DI float bf2f(short s){
  union { uint32_t u; float f; } v; v.u = ((uint32_t)(unsigned short)s) << 16; return v.f;
}
DI float sigm(float x){ return __fdividef(1.f, 1.f + __expf(-x)); }
DI float ftanh(float x){ return 1.f - __fdividef(2.f, __expf(2.f*x) + 1.f); }
DI float wsum(float v){
  #pragma unroll
  for (int m = 32; m > 0; m >>= 1) v += __shfl_xor(v, m, 64);
  return v;
}
DI float wmax(float v){
  #pragma unroll
  for (int m = 32; m > 0; m >>= 1) v = fmaxf(v, __shfl_xor(v, m, 64));
  return v;
}
DI f32x4 mfma16(bf16x8 a, bf16x8 b, f32x4 c){
  return __builtin_amdgcn_mfma_f32_16x16x32_bf16(a, b, c, 0, 0, 0);
}
DI i32x4 mfma_i8(i32x4 a, i32x4 b, i32x4 c){
  return __builtin_amdgcn_mfma_i32_16x16x64_i8(a, b, c, 0, 0, 0);
}
DI bf16x8 ldb(const short* __restrict__ W, int n0, int k0, int lane){
  return *(const bf16x8*)(W + (size_t)(n0 + (lane & 15)) * 512 + k0 + ((lane >> 4) << 3));
}
DI bf16x8 load_a32(const float* __restrict__ A, int ld, int m0, int k0, int lane){
  const float* p = A + (size_t)(m0 + (lane & 15)) * ld + k0 + ((lane >> 4) << 3);
  bf16x8 f;
  #pragma unroll
  for (int j = 0; j < 8; ++j) f[j] = f2bf(p[j]);
  return f;
}

// ---------------- elementwise / prep kernels ----------------

struct CvtJobs { const float* src[8]; short* dst[8]; int cum4[9]; };

__global__ __launch_bounds__(256) void k_cvt_multi(CvtJobs jb, int total4){
  int i = blockIdx.x * 256 + threadIdx.x;
  if (i >= total4) return;
  int j = 0;
  #pragma unroll
  for (int k = 0; k < 8; ++k) if (i >= jb.cum4[k + 1]) j = k + 1;
  int off = i - jb.cum4[j];
  float4 v = ((const float4*)jb.src[j])[off];
  s16x4 o; o[0] = f2bf(v.x); o[1] = f2bf(v.y); o[2] = f2bf(v.z); o[3] = f2bf(v.w);
  ((s16x4*)jb.dst[j])[off] = o;
}

__global__ __launch_bounds__(256) void k_tc(const float* __restrict__ W, short* __restrict__ WT){
  int i = blockIdx.x * 256 + threadIdx.x;
  int c = i >> 9, h = i & 511;
  WT[i] = f2bf(W[h * 512 + c]);
}

__global__ __launch_bounds__(256) void k_zero(float* __restrict__ p, int n){
  int i = blockIdx.x * 256 + threadIdx.x;
  if (i < n) p[i] = 0.f;
}

__global__ __launch_bounds__(256) void k_meanmix(const float* __restrict__ ctx, const float* __restrict__ mask,
                                                 const float* __restrict__ txt, float* __restrict__ mixed){
  int i = blockIdx.x * 256 + threadIdx.x;
  int b = i >> 9, c = i & 511;
  float s = 0.f;
  for (int t = 0; t < 64; ++t) s += ctx[(size_t)(t * 64 + b) * 512 + c];
  float dn = 0.f;
  for (int t = 0; t < 64; ++t) dn += mask[t * 64 + b];
  mixed[i] = 0.5f * (s / dn) + 0.5f * txt[i];
}

// per-row i8 quantization (rows of 512 fp32). one wave per row.
__global__ __launch_bounds__(256) void k_quant(const float* __restrict__ src, char* __restrict__ dst,
                                               float* __restrict__ scales, int nrows){
  int row = blockIdx.x * 4 + (threadIdx.x >> 6);
  int lane = threadIdx.x & 63;
  if (row >= nrows) return;
  const float* p = src + (size_t)row * 512 + lane * 8;
  float v[8]; float mx = 0.f;
  #pragma unroll
  for (int j = 0; j < 8; ++j){ v[j] = p[j]; mx = fmaxf(mx, fabsf(v[j])); }
  mx = wmax(mx);
  float inv = 127.f / fmaxf(mx, 1e-30f);
  u64 pk = 0;
  #pragma unroll
  for (int j = 0; j < 8; ++j){
    int q = (int)rintf(v[j] * inv);
    pk |= ((u64)(unsigned char)(char)q) << (8 * j);
  }
  *(u64*)(dst + (size_t)row * 512 + lane * 8) = pk;
  if (lane == 0) scales[row] = fmaxf(mx, 1e-30f) / 127.f;
}

// ---------------- generic wave-tile GEMMs (K = 512, fp32 A, bf16 W) ----------------

__global__ __launch_bounds__(256) void k_gemm_bt(const float* __restrict__ A, const short* __restrict__ W,
                                                 float* __restrict__ C, int N, int act){
  int wg = blockIdx.x * 4 + (threadIdx.x >> 6);
  int lane = threadIdx.x & 63;
  int ntiles = N >> 4;
  int mt = wg / ntiles, nt = wg - mt * ntiles;
  int m0 = mt << 4, n0 = nt << 4;
  f32x4 acc = {0.f, 0.f, 0.f, 0.f};
  for (int k = 0; k < 512; k += 32)
    acc = mfma16(load_a32(A, 512, m0, k, lane), ldb(W, n0, k, lane), acc);
  int col = n0 + (lane & 15);
  int r0 = m0 + ((lane >> 4) << 2);
  #pragma unroll
  for (int r = 0; r < 4; ++r){
    float v = acc[r];
    if (act) v = ftanh(v);
    C[(size_t)(r0 + r) * N + col] = v;
  }
}

__global__ __launch_bounds__(256) void k_gemm_bt_obf(const float* __restrict__ A, const short* __restrict__ W,
                                                     short* __restrict__ C, int N){
  int wg = blockIdx.x * 4 + (threadIdx.x >> 6);
  int lane = threadIdx.x & 63;
  int ntiles = N >> 4;
  int mt = wg / ntiles, nt = wg - mt * ntiles;
  int m0 = mt << 4, n0 = nt << 4;
  f32x4 acc = {0.f, 0.f, 0.f, 0.f};
  for (int k = 0; k < 512; k += 32)
    acc = mfma16(load_a32(A, 512, m0, k, lane), ldb(W, n0, k, lane), acc);
  int col = n0 + (lane & 15);
  int r0 = m0 + ((lane >> 4) << 2);
  #pragma unroll
  for (int r = 0; r < 4; ++r)
    C[(size_t)(r0 + r) * N + col] = f2bf(acc[r]);
}

__global__ __launch_bounds__(256) void k_gi0(const int* __restrict__ y, const float* __restrict__ emb,
                                             const short* __restrict__ W, const float* __restrict__ bias,
                                             float* __restrict__ C){
  int wg = blockIdx.x * 4 + (threadIdx.x >> 6);
  int lane = threadIdx.x & 63;
  int mt = wg / 96, nt = wg - mt * 96;
  int m0 = mt << 4, n0 = nt << 4;
  int yr = y[m0 + (lane & 15)];
  const float* arow = emb + (size_t)yr * 512;
  f32x4 acc = {0.f, 0.f, 0.f, 0.f};
  for (int k = 0; k < 512; k += 32){
    const float* p = arow + k + ((lane >> 4) << 3);
    bf16x8 a;
    #pragma unroll
    for (int j = 0; j < 8; ++j) a[j] = f2bf(p[j]);
    acc = mfma16(a, ldb(W, n0, k, lane), acc);
  }
  int col = n0 + (lane & 15);
  int r0 = m0 + ((lane >> 4) << 2);
  #pragma unroll
  for (int r = 0; r < 4; ++r)
    C[(size_t)(r0 + r) * 1536 + col] = acc[r] + bias[col];
}

// ---------------- persistent per-b recurrence (no cross-WG sync) ----------------

struct RB {
  const float* h0;        // [64][512]
  const float* gi0;       // [48][64][1536] (incl b_ih0)
  const char*  W8_hh0; const float* s_hh0;   // i8 [1536][512] + row scales
  const char*  W8_q;   const float* s_q;     // i8 [512][512]
  const char*  W8_hh1; const float* s_hh1;   // i8 [1536][512]
  const char*  W8_cb;  const float* s_cb;    // i8 [1536][512]
  const float* bhh0; const float* bih1; const float* bhh1;
  const short* ctx_proj;  // bf16 [s*64+b][512]
  const short* ctxbf;     // bf16 [s*64+b][512]
  const float* mask;      // [64][64] (s,b)
  const float* wmlp;      // [512]
  float* h2;              // [48][64][512]
};

// i8 matvec: out[j] = acc(j) * srow[j] * bscale for rows [rbase, rbase+16*ntiles)
DI void matvec_i8(const char* __restrict__ W8, const float* __restrict__ srow,
                  const int* vq, float bscale, float* outS, int rbase, int ntiles, int lane){
  for (int t = 0; t < ntiles; ++t){
    int j0 = rbase + t * 16;
    i32x4 acc = {0, 0, 0, 0};
    #pragma unroll
    for (int kk = 0; kk < 8; ++kk){
      i32x4 af = *(const i32x4*)(W8 + (size_t)(j0 + (lane & 15)) * 512 + kk * 64 + ((lane >> 4) << 4));
      i32x4 bq = *(const i32x4*)((const char*)vq + kk * 64 + ((lane >> 4) << 4));
      acc = mfma_i8(af, bq, acc);
    }
    if ((lane & 15) == 0){
      int jr = j0 + ((lane >> 4) << 2);
      #pragma unroll
      for (int r = 0; r < 4; ++r)
        outS[jr + r] = (float)acc[r] * srow[jr + r] * bscale;
    }
  }
}

__global__ __launch_bounds__(256, 1) void k_recur(RB a){
  __shared__ float hS[512], h1S[512], qS[512];     // qS reused as catt
  __shared__ float g0S[1536], g1S[1536];
  __shared__ int   hqI[128], cqI[128];
  __shared__ float wmS[512], mkS[64], scS[64], alS[64], red[4], csc[2];
  const int b = blockIdx.x, tid = threadIdx.x;
  const int wv = tid >> 6, lane = tid & 63;
  const float INV127 = 1.f / 127.f;

  hS[tid] = a.h0[(size_t)b * 512 + tid];
  hS[tid + 256] = a.h0[(size_t)b * 512 + tid + 256];
  wmS[tid] = a.wmlp[tid]; wmS[tid + 256] = a.wmlp[tid + 256];
  if (tid < 64) mkS[tid] = a.mask[(tid << 6) + b];
  __syncthreads();

  #pragma unroll 1
  for (int t = 0; t < 48; ++t){
    // quantize h (|h|<1) -> hqI
    if (tid < 128){
      u32 pk = 0;
      #pragma unroll
      for (int u = 0; u < 4; ++u){
        int q = (int)rintf(hS[tid * 4 + u] * 127.f);
        pk |= ((u32)(unsigned char)(char)q) << (8 * u);
      }
      hqI[tid] = (int)pk;
    }
    __syncthreads();
    // gh0 = Whh0 @ h
    matvec_i8(a.W8_hh0, a.s_hh0, hqI, INV127, g0S, wv * 384, 24, lane);
    __syncthreads();
    // gru0 combine -> h1
    const float* gi = a.gi0 + (size_t)t * 98304 + (size_t)b * 1536;
    #pragma unroll
    for (int half = 0; half < 2; ++half){
      int i = tid + half * 256;
      float rr = sigm(gi[i] + g0S[i] + a.bhh0[i]);
      float zz = sigm(gi[512 + i] + g0S[512 + i] + a.bhh0[512 + i]);
      float nn = ftanh(gi[1024 + i] + rr * (g0S[1024 + i] + a.bhh0[1024 + i]));
      h1S[i] = (1.f - zz) * nn + zz * hS[i];
    }
    __syncthreads();
    // quantize h1
    if (tid < 128){
      u32 pk = 0;
      #pragma unroll
      for (int u = 0; u < 4; ++u){
        int q = (int)rintf(h1S[tid * 4 + u] * 127.f);
        pk |= ((u32)(unsigned char)(char)q) << (8 * u);
      }
      hqI[tid] = (int)pk;
    }
    __syncthreads();
    // q = Wq @ h1 ; gh1 = Whh1 @ h1
    matvec_i8(a.W8_q,   a.s_q,   hqI, INV127, qS,  wv * 128, 8,  lane);
    matvec_i8(a.W8_hh1, a.s_hh1, hqI, INV127, g1S, wv * 384, 24, lane);
    __syncthreads();
    // scores
    for (int i = 0; i < 16; ++i){
      int s = (wv << 4) + i;
      bf16x8 c8 = *(const bf16x8*)(a.ctx_proj + (size_t)((s << 6) + b) * 512 + lane * 8);
      float p = 0.f;
      #pragma unroll
      for (int j = 0; j < 8; ++j){
        int m = lane * 8 + j;
        p += ftanh(bf2f(c8[j]) + qS[m]) * wmS[m];
      }
      p = wsum(p);
      if (lane == 0) scS[s] = p;
    }
    __syncthreads();
    if (tid < 64){
      float v = (mkS[tid] > 0.f) ? scS[tid] : -100000000.0f;
      float mx = wmax(v);
      float e = __expf(v - mx);
      float se = wsum(e);
      alS[tid] = e / se;
    }
    __syncthreads();
    // catt -> qS (q no longer needed), track absmax
    float am = 0.f;
    #pragma unroll
    for (int half = 0; half < 2; ++half){
      int c = tid + half * 256;
      float acc2 = 0.f;
      for (int s = 0; s < 64; ++s)
        acc2 += alS[s] * bf2f(a.ctxbf[(size_t)((s << 6) + b) * 512 + c]);
      qS[c] = acc2;
      am = fmaxf(am, fabsf(acc2));
    }
    am = wmax(am);
    if (lane == 0) red[wv] = am;
    __syncthreads();
    if (tid == 0){
      float m = fmaxf(fmaxf(red[0], red[1]), fmaxf(red[2], red[3]));
      m = fmaxf(m, 1e-30f);
      csc[0] = m / 127.f;       // bscale
      csc[1] = 127.f / m;       // inv for quant
    }
    __syncthreads();
    if (tid < 128){
      float inv = csc[1];
      u32 pk = 0;
      #pragma unroll
      for (int u = 0; u < 4; ++u){
        int q = (int)rintf(qS[tid * 4 + u] * inv);
        pk |= ((u32)(unsigned char)(char)q) << (8 * u);
      }
      cqI[tid] = (int)pk;
    }
    __syncthreads();
    // gi1 = Wcomb @ catt
    matvec_i8(a.W8_cb, a.s_cb, cqI, csc[0], g0S, wv * 384, 24, lane);
    __syncthreads();
    // gru1 combine -> h2, update h
    float* h2t = a.h2 + (size_t)t * 32768 + (size_t)b * 512;
    #pragma unroll
    for (int half = 0; half < 2; ++half){
      int i = tid + half * 256;
      float rr = sigm(g0S[i] + a.bih1[i] + g1S[i] + a.bhh1[i]);
      float zz = sigm(g0S[512 + i] + a.bih1[512 + i] + g1S[512 + i] + a.bhh1[512 + i]);
      float nn = ftanh(g0S[1024 + i] + a.bih1[1024 + i] + rr * (g1S[1024 + i] + a.bhh1[1024 + i]));
      float hv = (1.f - zz) * nn + zz * h1S[i];
      hS[i] = hv;
      h2t[i] = hv;
    }
    __syncthreads();
  }
}

// ---------------- phase 2 ----------------

__global__ __launch_bounds__(256) void k_logit(const float* __restrict__ A, const short* __restrict__ W,
                                               const float* __restrict__ bias, short* __restrict__ tlb,
                                               float* __restrict__ tlf){
  int wg = blockIdx.x * 4 + (threadIdx.x >> 6);
  int lane = threadIdx.x & 63;
  int mt = wg >> 5, nt = wg & 31;
  int m0 = mt << 4, n0 = nt << 4;
  f32x4 acc = {0.f, 0.f, 0.f, 0.f};
  for (int k = 0; k < 512; k += 32)
    acc = mfma16(load_a32(A, 512, m0, k, lane), ldb(W, n0, k, lane), acc);
  int col = n0 + (lane & 15);
  int r0 = m0 + ((lane >> 4) << 2);
  #pragma unroll
  for (int r = 0; r < 4; ++r){
    float v = ftanh(acc[r] + bias[col]);
    size_t o = (size_t)(r0 + r) * 512 + col;
    tlf[o] = v; tlb[o] = f2bf(v);
  }
}

__global__ __launch_bounds__(256) void k_sumexp(const short* __restrict__ A, const short* __restrict__ B,
                                                const float* __restrict__ bias, float* __restrict__ sumexp){
  __shared__ short lA[128 * 40];
  __shared__ short lB[128 * 40];
  int bm = blockIdx.x % 24, bn = blockIdx.x / 24;
  int m0 = bm * 128, n0 = bn * 128;
  int tid = threadIdx.x, w = tid >> 6, lane = tid & 63;
  int mq = (w >> 1) * 64, nq = (w & 1) * 64;
  f32x4 acc[4][4];
  #pragma unroll
  for (int i = 0; i < 4; ++i)
    #pragma unroll
    for (int j = 0; j < 4; ++j) acc[i][j] = (f32x4){0.f, 0.f, 0.f, 0.f};

  for (int k0 = 0; k0 < 512; k0 += 32){
    __syncthreads();
    #pragma unroll
    for (int i = 0; i < 2; ++i){
      int idx = tid * 8 + i * 2048;
      int row = idx >> 5, colh = idx & 31;
      *(bf16x8*)&lA[row * 40 + colh] = *(const bf16x8*)(A + (size_t)(m0 + row) * 512 + k0 + colh);
      *(bf16x8*)&lB[row * 40 + colh] = *(const bf16x8*)(B + (size_t)(n0 + row) * 512 + k0 + colh);
    }
    __syncthreads();
    bf16x8 af[4], bfr[4];
    #pragma unroll
    for (int x = 0; x < 4; ++x){
      af[x]  = *(const bf16x8*)&lA[(mq + x * 16 + (lane & 15)) * 40 + ((lane >> 4) << 3)];
      bfr[x] = *(const bf16x8*)&lB[(nq + x * 16 + (lane & 15)) * 40 + ((lane >> 4) << 3)];
    }
    #pragma unroll
    for (int mi = 0; mi < 4; ++mi)
      #pragma unroll
      for (int ni = 0; ni < 4; ++ni)
        acc[mi][ni] = mfma16(af[mi], bfr[ni], acc[mi][ni]);
  }

  #pragma unroll
  for (int mi = 0; mi < 4; ++mi){
    #pragma unroll
    for (int r = 0; r < 4; ++r){
      float e = 0.f;
      #pragma unroll
      for (int ni = 0; ni < 4; ++ni){
        int col = n0 + nq + ni * 16 + (lane & 15);
        e += __expf(acc[mi][ni][r] + bias[col]);
      }
      e += __shfl_xor(e, 1, 64); e += __shfl_xor(e, 2, 64);
      e += __shfl_xor(e, 4, 64); e += __shfl_xor(e, 8, 64);
      if ((lane & 15) == 0){
        int row = m0 + mq + mi * 16 + ((lane >> 4) << 2) + r;
        atomicAdd(&sumexp[row], e);
      }
    }
  }
}

__global__ __launch_bounds__(256) void k_loss(const float* __restrict__ tlf, const float* __restrict__ Wop,
                                              const float* __restrict__ bop, const int* __restrict__ y,
                                              const float* __restrict__ sumexp, float* __restrict__ loss){
  int step = blockIdx.x;
  int w = threadIdx.x >> 6, lane = threadIdx.x & 63;
  __shared__ float accw[4];
  float part = 0.f;
  for (int b = w; b < 64; b += 4){
    int row = step * 64 + b;
    int t = y[(step + 1) * 64 + b];
    if (t != 0){
      const float* a = tlf + (size_t)row * 512 + lane * 8;
      const float* wr = Wop + (size_t)t * 512 + lane * 8;
      float d = 0.f;
      #pragma unroll
      for (int j = 0; j < 8; ++j) d += a[j] * wr[j];
      d = wsum(d);
      if (lane == 0) part += d + bop[t] - __logf(sumexp[row]);
    }
  }
  if (lane == 0) accw[w] = part;
  __syncthreads();
  if (threadIdx.x == 0) atomicAdd(loss, -(accw[0] + accw[1] + accw[2] + accw[3]));
}

__global__ void k_final(const float* __restrict__ loss, float* __restrict__ out){
  if (threadIdx.x == 0 && blockIdx.x == 0) out[0] = loss[0];
}

// ---------------- host launch ----------------

extern "C" void kernel_launch(void* const* d_in, const int* in_sizes, int n_in,
                              void* d_out, int out_size, void* d_ws, size_t ws_size,
                              hipStream_t stream) {
  const float* ctx       = (const float*)d_in[0];
  const float* ctx_mask  = (const float*)d_in[1];
  const float* txt_ctx   = (const float*)d_in[2];
  const int*   y         = (const int*)d_in[3];
  const float* emb       = (const float*)d_in[4];
  const float* W_ctx2ctx = (const float*)d_in[5];
  const float* W_hid2ctx = (const float*)d_in[6];
  const float* w_mlp     = (const float*)d_in[7];
  const float* W_ctx2hid = (const float*)d_in[8];
  const float* W_dec_init= (const float*)d_in[9];
  const float* W_ih0     = (const float*)d_in[10];
  const float* W_hh0     = (const float*)d_in[11];
  const float* b_ih0     = (const float*)d_in[12];
  const float* b_hh0     = (const float*)d_in[13];
  const float* W_ih1     = (const float*)d_in[14];
  const float* W_hh1     = (const float*)d_in[15];
  const float* b_ih1     = (const float*)d_in[16];
  const float* b_hh1     = (const float*)d_in[17];
  const float* W_hid2out = (const float*)d_in[18];
  const float* b_hid2out = (const float*)d_in[19];
  const float* W_out2prob= (const float*)d_in[20];
  const float* b_out2prob= (const float*)d_in[21];
  float* out = (float*)d_out;

  char* p = (char*)d_ws;
  auto alloc = [&](size_t n){ char* r = p; p += (n + 255) & ~(size_t)255; return r; };
  short* Wb_hid2out = (short*)alloc((size_t)512 * 512 * 2);
  short* Wb_dec     = (short*)alloc((size_t)512 * 512 * 2);
  short* Wb_c2c     = (short*)alloc((size_t)512 * 512 * 2);
  short* Wb_ih0     = (short*)alloc((size_t)1536 * 512 * 2);
  short* Wb_o2p     = (short*)alloc((size_t)32000 * 512 * 2);
  short* ctxbf      = (short*)alloc((size_t)4096 * 512 * 2);
  short* WctT       = (short*)alloc((size_t)512 * 512 * 2);
  float* Wcomb_f    = (float*)alloc((size_t)1536 * 512 * 4);
  short* ctx_projbf = (short*)alloc((size_t)4096 * 512 * 2);
  char*  W8_hh0     = alloc((size_t)1536 * 512);
  char*  W8_q       = alloc((size_t)512 * 512);
  char*  W8_hh1     = alloc((size_t)1536 * 512);
  char*  W8_cb      = alloc((size_t)1536 * 512);
  float* s_hh0      = (float*)alloc((size_t)1536 * 4);
  float* s_q        = (float*)alloc((size_t)512 * 4);
  float* s_hh1      = (float*)alloc((size_t)1536 * 4);
  float* s_cb       = (float*)alloc((size_t)1536 * 4);
  float* gi0_all    = (float*)alloc((size_t)3072 * 1536 * 4);
  float* mixed      = (float*)alloc((size_t)64 * 512 * 4);
  float* h0buf      = (float*)alloc((size_t)64 * 512 * 4);
  float* h2_all     = (float*)alloc((size_t)3072 * 512 * 4);
  short* tl_bf      = (short*)alloc((size_t)3072 * 512 * 2);
  float* tl_f       = (float*)alloc((size_t)3072 * 512 * 4);
  float* zreg       = (float*)alloc((size_t)3073 * 4);
  float* sumexp     = zreg;
  float* lossbuf    = zreg + 3072;

  dim3 blk(256);
  // ---- phase 0 ----
  CvtJobs jb;
  const float* srcs[6] = {W_hid2out, W_dec_init, W_ctx2ctx, W_ih0, W_out2prob, ctx};
  short* dsts[6] = {Wb_hid2out, Wb_dec, Wb_c2c, Wb_ih0, Wb_o2p, ctxbf};
  int sizes4[6] = {512*512/4, 512*512/4, 512*512/4, 1536*512/4, 32000*512/4, 4096*512/4};
  int cum = 0;
  for (int i = 0; i < 6; ++i){ jb.src[i] = srcs[i]; jb.dst[i] = dsts[i]; jb.cum4[i] = cum; cum += sizes4[i]; }
  jb.src[6] = srcs[0]; jb.dst[6] = dsts[0]; jb.src[7] = srcs[0]; jb.dst[7] = dsts[0];
  jb.cum4[6] = cum; jb.cum4[7] = cum; jb.cum4[8] = cum;
  k_cvt_multi<<<dim3((cum + 255) / 256), blk, 0, stream>>>(jb, cum);
  k_tc<<<dim3(1024), blk, 0, stream>>>(W_ctx2hid, WctT);
  k_gemm_bt<<<dim3(768), blk, 0, stream>>>(W_ih1, WctT, Wcomb_f, 512, 0);        // W_comb fp32
  k_meanmix<<<dim3(128), blk, 0, stream>>>(ctx, ctx_mask, txt_ctx, mixed);
  k_gemm_bt<<<dim3(32), blk, 0, stream>>>(mixed, Wb_dec, h0buf, 512, 1);         // h0 = tanh(.)
  k_gemm_bt_obf<<<dim3(2048), blk, 0, stream>>>(ctx, Wb_c2c, ctx_projbf, 512);   // ctx_proj bf16
  k_gi0<<<dim3(4608), blk, 0, stream>>>(y, emb, Wb_ih0, b_ih0, gi0_all);
  k_quant<<<dim3(384), blk, 0, stream>>>(W_hh0,     W8_hh0, s_hh0, 1536);
  k_quant<<<dim3(128), blk, 0, stream>>>(W_hid2ctx, W8_q,   s_q,   512);
  k_quant<<<dim3(384), blk, 0, stream>>>(W_hh1,     W8_hh1, s_hh1, 1536);
  k_quant<<<dim3(384), blk, 0, stream>>>(Wcomb_f,   W8_cb,  s_cb,  1536);
  k_zero<<<dim3(13), blk, 0, stream>>>(zreg, 3073);

  // ---- phase 1: per-b persistent recurrence (plain launch, no grid sync) ----
  RB rb;
  rb.h0 = h0buf; rb.gi0 = gi0_all;
  rb.W8_hh0 = W8_hh0; rb.s_hh0 = s_hh0;
  rb.W8_q = W8_q; rb.s_q = s_q;
  rb.W8_hh1 = W8_hh1; rb.s_hh1 = s_hh1;
  rb.W8_cb = W8_cb; rb.s_cb = s_cb;
  rb.bhh0 = b_hh0; rb.bih1 = b_ih1; rb.bhh1 = b_hh1;
  rb.ctx_proj = ctx_projbf; rb.ctxbf = ctxbf;
  rb.mask = ctx_mask; rb.wmlp = w_mlp;
  rb.h2 = h2_all;
  k_recur<<<dim3(64), blk, 0, stream>>>(rb);

  // ---- phase 2 ----
  k_logit<<<dim3(1536), blk, 0, stream>>>(h2_all, Wb_hid2out, b_hid2out, tl_bf, tl_f);
  k_sumexp<<<dim3(6000), blk, 0, stream>>>(tl_bf, Wb_o2p, b_out2prob, sumexp);
  k_loss<<<dim3(48), blk, 0, stream>>>(tl_f, W_out2prob, b_out2prob, y, sumexp, lossbuf);
  k_final<<<dim3(1), blk, 0, stream>>>(lossbuf, out);
}